// Round 15
// baseline (1162.390 us; speedup 1.0000x reference)
//
#include <hip/hip_runtime.h>
#include <hip/hip_bf16.h>

// ============================================================================
// PPO agent fused forward (round 15):
//  r14 (2 row-tiles/wave, A in LDS) killed the spill (WRITE 62MB) -> 1110us.
//  Now latency-bound at 1 wave/SIMD (LDS-capped, irreducible for this
//  dataflow) -> shorten the per-wave serial path:
//   (1) per-layer params (bias/gam/bet) staged once into a 3KB per-wave LDS
//       slot; in-loop reads become ds_read_b32 (was global L2-latency loads).
//   (2) pack2 via __float22bfloat162_rn -> v_cvt_pk_bf16_f32 (1 op vs ~4).
//   (3) nt processed in even/odd pairs: pre-LN stash writes ONE b32 per
//       (row, pair) instead of two b16 (layout identical by k-perm
//       construction; 2-way bank pattern = free).
//  LDS 40KB/wave -> 80KB/block -> 2 blocks/CU (unchanged). Same rounding
//  points as r14 -> absmax ~0.125.
// ============================================================================

#define T_SZ 524288
#define GL 0.9405f   // GAMMA*LAM

typedef __attribute__((ext_vector_type(8))) short bf16x8;   // 8 bf16 (4 VGPRs)
typedef __attribute__((ext_vector_type(4))) float f32x4;

// ws layout (bf16 elements); weights in ntile/fragment-major layout (r13)
#define OFF_AW1T 0        // 256x64
#define OFF_AW2T 16384    // 256x256
#define OFF_AW3T 81920    // 32x256 (rows >=18 zero)
#define OFF_CW1T 90112    // 256x64
#define OFF_CW2T 106496   // 256x256
#define OFF_CW3T 172032   // 16x256 (rows >=1 zero)
#define W_ELEMS  176128
#define OFF_DELTAS_BYTES 352256

// k = p*32 + h*16 + w -> pos = p*32 + w*2 + h (applied to A and B alike)
__device__ __forceinline__ int perm_k(int k) {
  return (k & ~31) | ((k & 15) << 1) | ((k >> 4) & 1);
}

__device__ __forceinline__ unsigned pack2(float a, float b) {
  __hip_bfloat162 h = __float22bfloat162_rn(float2{a, b});   // v_cvt_pk_bf16_f32
  union { __hip_bfloat162 h2; unsigned u; } x;
  x.h2 = h;
  return x.u;
}

__device__ __forceinline__ void unpack2(unsigned u, float& a, float& b) {
  union { unsigned u; float f; } x, y;
  x.u = u << 16; y.u = u & 0xFFFF0000u;
  a = x.f; b = y.f;
}

// ---------------------------------------------------------------------------
// stage X: 32 rows x 64 fp32 -> k-permuted swizzled bf16 LDS [32][128B]
__device__ __forceinline__ void stage_x(const float* __restrict__ src,
                                        char* XB, int c, int q) {
#pragma unroll
  for (int t = 0; t < 2; ++t) {
    const int row = t * 16 + c;
    const float* rp = src + (size_t)row * 64;
#pragma unroll
    for (int ks = 0; ks < 2; ++ks) {
      float4 a = *(const float4*)(rp + ks * 32 + 4 * q);
      float4 b = *(const float4*)(rp + ks * 32 + 4 * q + 16);
      unsigned u[4];
      u[0] = pack2(a.x, b.x); u[1] = pack2(a.y, b.y);
      u[2] = pack2(a.z, b.z); u[3] = pack2(a.w, b.w);
      *(uint4*)(XB + row * 128 + ((ks * 64 + q * 16) ^ ((row & 7) << 4))) =
          *(uint4*)u;
    }
  }
}

// ---------------------------------------------------------------------------
// Linear(K->256)+bias+LN+ReLU for 2 row-tiles, nt in even/odd pairs.
// A from LDS (astr bytes/row), B from global fragment-major, params from PB.
template<int K, int UNR>
__device__ __forceinline__ void layer2t(const char* A, int astr,
    const char* __restrict__ W,
    const float* __restrict__ bias, const float* __restrict__ gam,
    const float* __restrict__ bet, char* O, char* PB,
    int c, int q, int lane) {
  // stage params (bias@0, gam@1024, bet@2048) -- 3 coalesced loads
  {
    float4 b4 = *(const float4*)(bias + lane * 4);
    float4 g4 = *(const float4*)(gam + lane * 4);
    float4 n4 = *(const float4*)(bet + lane * 4);
    *(float4*)(PB + lane * 16) = b4;
    *(float4*)(PB + 1024 + lane * 16) = g4;
    *(float4*)(PB + 2048 + lane * 16) = n4;
  }
  const float* PF = (const float*)PB;
  constexpr int NK = K / 32;
  float s0[4] = {0, 0, 0, 0}, ss0[4] = {0, 0, 0, 0};
  float s1[4] = {0, 0, 0, 0}, ss1[4] = {0, 0, 0, 0};
  const int sw = (c & 7) << 4;           // (16+c)&7 == c&7
#pragma unroll UNR
  for (int g = 0; g < 8; ++g) {          // nt pair (2g, 2g+1)
    const char* We = W + (size_t)(2 * g) * (K * 32);
    const char* Wo = We + (size_t)(K * 32);
    f32x4 e0 = {0.f, 0.f, 0.f, 0.f}, e1 = {0.f, 0.f, 0.f, 0.f};
    f32x4 o0 = {0.f, 0.f, 0.f, 0.f}, o1 = {0.f, 0.f, 0.f, 0.f};
#pragma unroll
    for (int ks = 0; ks < NK; ++ks) {
      bf16x8 be = *(const bf16x8*)(We + ks * 1024 + lane * 16);
      bf16x8 bo = *(const bf16x8*)(Wo + ks * 1024 + lane * 16);
      const int cb = (ks * 64 + q * 16) ^ sw;
      bf16x8 a0 = *(const bf16x8*)(A + (size_t)c * astr + cb);
      bf16x8 a1 = *(const bf16x8*)(A + (size_t)(16 + c) * astr + cb);
      e0 = __builtin_amdgcn_mfma_f32_16x16x32_bf16(a0, be, e0, 0, 0, 0);
      e1 = __builtin_amdgcn_mfma_f32_16x16x32_bf16(a1, be, e1, 0, 0, 0);
      o0 = __builtin_amdgcn_mfma_f32_16x16x32_bf16(a0, bo, o0, 0, 0, 0);
      o1 = __builtin_amdgcn_mfma_f32_16x16x32_bf16(a1, bo, o1, 0, 0, 0);
    }
    const float bbe = PF[2 * g * 16 + c];        // ds_read_b32
    const float bbo = PF[(2 * g + 1) * 16 + c];
#pragma unroll
    for (int r = 0; r < 4; ++r) {
      float ve0 = e0[r] + bbe, vo0 = o0[r] + bbo;   // tile0: even, odd cols
      float ve1 = e1[r] + bbe, vo1 = o1[r] + bbo;   // tile1
      s0[r] += ve0 + vo0; ss0[r] += ve0 * ve0 + vo0 * vo0;
      s1[r] += ve1 + vo1; ss1[r] += ve1 * ve1 + vo1 * vo1;
      const int rsw = ((q * 4 + r) & 7) << 4;       // same for row and row+16
      const int cb = (g * 64 + c * 4) ^ rsw;
      *(unsigned*)(O + (q * 4 + r) * 512 + cb) = pack2(ve0, vo0);
      *(unsigned*)(O + (16 + q * 4 + r) * 512 + cb) = pack2(ve1, vo1);
    }
  }
  // stats over the 16 c-lanes (lane = q*16+c; xor m<16 flips c only)
#pragma unroll
  for (int m = 1; m < 16; m <<= 1) {
#pragma unroll
    for (int r = 0; r < 4; ++r) {
      s0[r] += __shfl_xor(s0[r], m, 64); ss0[r] += __shfl_xor(ss0[r], m, 64);
      s1[r] += __shfl_xor(s1[r], m, 64); ss1[r] += __shfl_xor(ss1[r], m, 64);
    }
  }
#pragma unroll
  for (int r = 0; r < 4; ++r) {
    float mu0 = s0[r] * (1.f / 256.f);
    ss0[r] = rsqrtf(ss0[r] * (1.f / 256.f) - mu0 * mu0 + 1e-5f); s0[r] = mu0;
    float mu1 = s1[r] * (1.f / 256.f);
    ss1[r] = rsqrtf(ss1[r] * (1.f / 256.f) - mu1 * mu1 + 1e-5f); s1[r] = mu1;
  }
  // pass-2: in-LDS RMW normalize+ReLU (lane-local stats, own rows)
#pragma unroll
  for (int p = 0; p < 8; ++p) {
    const float g0  = PF[256 + p * 32 + c],      b0v = PF[512 + p * 32 + c];
    const float g1  = PF[256 + p * 32 + 16 + c], b1v = PF[512 + p * 32 + 16 + c];
#pragma unroll
    for (int r = 0; r < 4; ++r) {
      const int cb = (p * 64 + c * 4) ^ (((q * 4 + r) & 7) << 4);
      unsigned* ap0 = (unsigned*)(O + (q * 4 + r) * 512 + cb);
      unsigned* ap1 = (unsigned*)(O + (16 + q * 4 + r) * 512 + cb);
      float v0, v1;
      unpack2(*ap0, v0, v1);
      v0 = fmaxf((v0 - s0[r]) * ss0[r] * g0 + b0v, 0.f);
      v1 = fmaxf((v1 - s0[r]) * ss0[r] * g1 + b1v, 0.f);
      *ap0 = pack2(v0, v1);
      unpack2(*ap1, v0, v1);
      v0 = fmaxf((v0 - s1[r]) * ss1[r] * g0 + b0v, 0.f);
      v1 = fmaxf((v1 - s1[r]) * ss1[r] * g1 + b1v, 0.f);
      *ap1 = pack2(v0, v1);
    }
  }
}

// small final GEMM: NT ntiles, K=256, 2 row-tiles, A from LDS (stride 512)
template<int NT>
__device__ __forceinline__ void run_small2(const char* A,
    const char* __restrict__ W, int c, int q, int lane,
    f32x4* o0, f32x4* o1) {
  const int sw = (c & 7) << 4;
#pragma unroll
  for (int nt = 0; nt < NT; ++nt) {
    o0[nt] = (f32x4){0.f, 0.f, 0.f, 0.f};
    o1[nt] = (f32x4){0.f, 0.f, 0.f, 0.f};
  }
#pragma unroll
  for (int nt = 0; nt < NT; ++nt) {
    const char* Wn = W + (size_t)nt * 8192;
#pragma unroll
    for (int ks = 0; ks < 8; ++ks) {
      bf16x8 b = *(const bf16x8*)(Wn + ks * 1024 + lane * 16);
      const int cb = (ks * 64 + q * 16) ^ sw;
      bf16x8 a0 = *(const bf16x8*)(A + (size_t)c * 512 + cb);
      bf16x8 a1 = *(const bf16x8*)(A + (size_t)(16 + c) * 512 + cb);
      o0[nt] = __builtin_amdgcn_mfma_f32_16x16x32_bf16(a0, b, o0[nt], 0, 0, 0);
      o1[nt] = __builtin_amdgcn_mfma_f32_16x16x32_bf16(a1, b, o1[nt], 0, 0, 0);
    }
  }
}

__device__ __forceinline__ void softmax_write(f32x4* acc3,
    const float* __restrict__ ab3, float* __restrict__ out,
    int grow0, int c, int q) {
  float b0 = ab3[c];
  float b1 = (c < 2) ? ab3[16 + c] : 0.f;
#pragma unroll
  for (int r = 0; r < 4; ++r) {
    float x0 = acc3[0][r] + b0;
    float x1 = (c < 2) ? (acc3[1][r] + b1) : -1e30f;
    float mx = fmaxf(x0, x1);
#pragma unroll
    for (int m = 1; m < 16; m <<= 1) mx = fmaxf(mx, __shfl_xor(mx, m, 64));
    float e0 = __expf(x0 - mx);
    float e1 = (c < 2) ? __expf(x1 - mx) : 0.f;
    float sm = e0 + e1;
#pragma unroll
    for (int m = 1; m < 16; m <<= 1) sm += __shfl_xor(sm, m, 64);
    float inv = 1.f / sm;
    int gr = grow0 + q * 4 + r;
    out[(size_t)gr * 20 + c] = e0 * inv;
    if (c < 2) out[(size_t)gr * 20 + 16 + c] = e1 * inv;
  }
}

// ---------------------------------------------------------------------------
// prep: ntile/fragment-major (r13/r14, verified). (n,k) of [N][K]:
// nt=n>>4, cc=n&15; kp=perm_k(k): ks=kp>>5, qq=(kp&31)>>3, e=kp&7
// -> elem = MO + nt*(16*K) + ks*512 + (qq*16+cc)*8 + e.
__device__ __forceinline__ int frag_idx(int mo, int K, int n, int k) {
  const int kp = perm_k(k);
  const int nt = n >> 4, cc = n & 15;
  const int ks = kp >> 5, w = kp & 31, qq = w >> 3, e = w & 7;
  return mo + nt * (16 * K) + ks * 512 + (qq * 16 + cc) * 8 + e;
}

__global__ void prep_weights(const float* __restrict__ aw1, const float* __restrict__ aw2,
                             const float* __restrict__ aw3, const float* __restrict__ cw1,
                             const float* __restrict__ cw2, const float* __restrict__ cw3,
                             __hip_bfloat16* __restrict__ wb) {
  int i = blockIdx.x * 256 + threadIdx.x;
  if (i >= W_ELEMS) return;
  float v; int dst;
  if (i < OFF_AW2T)      { int j = i;            int n = j >> 6, k = j & 63;  v = aw1[k * 256 + n];                 dst = frag_idx(OFF_AW1T, 64,  n, k); }
  else if (i < OFF_AW3T) { int j = i - OFF_AW2T; int n = j >> 8, k = j & 255; v = aw2[k * 256 + n];                 dst = frag_idx(OFF_AW2T, 256, n, k); }
  else if (i < OFF_CW1T) { int j = i - OFF_AW3T; int n = j >> 8, k = j & 255; v = (n < 18) ? aw3[k * 18 + n] : 0.f; dst = frag_idx(OFF_AW3T, 256, n, k); }
  else if (i < OFF_CW2T) { int j = i - OFF_CW1T; int n = j >> 6, k = j & 63;  v = cw1[k * 256 + n];                 dst = frag_idx(OFF_CW1T, 64,  n, k); }
  else if (i < OFF_CW3T) { int j = i - OFF_CW2T; int n = j >> 8, k = j & 255; v = cw2[k * 256 + n];                 dst = frag_idx(OFF_CW2T, 256, n, k); }
  else                   { int j = i - OFF_CW3T; int n = j >> 8, k = j & 255; v = (n == 0) ? cw3[k] : 0.f;          dst = frag_idx(OFF_CW3T, 256, n, k); }
  wb[dst] = __float2bfloat16(v);
}

// ---------------------------------------------------------------------------
__global__ __launch_bounds__(128, 2) void mlp_kernel(
    const float* __restrict__ states, const float* __restrict__ next_states,
    const float* __restrict__ rewards, const float* __restrict__ masks,
    const float* __restrict__ ab1, const float* __restrict__ ag1, const float* __restrict__ an1,
    const float* __restrict__ ab2, const float* __restrict__ ag2, const float* __restrict__ an2,
    const float* __restrict__ ab3,
    const float* __restrict__ cb1, const float* __restrict__ cg1, const float* __restrict__ cn1,
    const float* __restrict__ cb2, const float* __restrict__ cg2, const float* __restrict__ cn2,
    const float* __restrict__ cb3,
    const __hip_bfloat16* __restrict__ wbuf,
    float* __restrict__ deltas, float* __restrict__ out) {
  __shared__ char LB[2][40960];   // per wave: XB 4K | A0 16K | A1 16K | PB 3K(+pad)
  const int tid = threadIdx.x;
  const int wave = tid >> 6, lane = tid & 63;
  const int c = lane & 15, q = lane >> 4;
  char* XB = LB[wave];
  char* A0 = LB[wave] + 4096;
  char* A1 = LB[wave] + 4096 + 16384;
  char* PB = LB[wave] + 4096 + 32768;
  const char* W = (const char*)wbuf;
  const int base = blockIdx.x * 64 + wave * 32;   // 32 timesteps per wave

  // ---- X(states) staged once (actor-L1 + critic-L1 share it) ----
  stage_x(states + (size_t)base * 64, XB, c, q);

  // ---- ACTOR(states) ----
  layer2t<64, 2>(XB, 128, W + OFF_AW1T * 2, ab1, ag1, an1, A0, PB, c, q, lane);
  __builtin_amdgcn_sched_barrier(0);
  layer2t<256, 1>(A0, 512, W + OFF_AW2T * 2, ab2, ag2, an2, A1, PB, c, q, lane);
  __builtin_amdgcn_sched_barrier(0);
  {
    f32x4 p0[2], p1[2];
    run_small2<2>(A1, W + OFF_AW3T * 2, c, q, lane, p0, p1);
    softmax_write(p0, ab3, out, base, c, q);
    softmax_write(p1, ab3, out, base + 16, c, q);
  }
  __builtin_amdgcn_sched_barrier(0);

  // ---- CRITIC(states) ---- (XB still intact)
  layer2t<64, 2>(XB, 128, W + OFF_CW1T * 2, cb1, cg1, cn1, A0, PB, c, q, lane);
  __builtin_amdgcn_sched_barrier(0);
  layer2t<256, 1>(A0, 512, W + OFF_CW2T * 2, cb2, cg2, cn2, A1, PB, c, q, lane);
  __builtin_amdgcn_sched_barrier(0);
  float vst0[4], vst1[4];
  {
    f32x4 v0[1], v1[1];
    run_small2<1>(A1, W + OFF_CW3T * 2, c, q, lane, v0, v1);
    const float b3 = cb3[0];
#pragma unroll
    for (int r = 0; r < 4; ++r) { vst0[r] = v0[0][r] + b3; vst1[r] = v1[0][r] + b3; }
  }
  __builtin_amdgcn_sched_barrier(0);

  // ---- CRITIC(next_states) ----
  stage_x(next_states + (size_t)base * 64, XB, c, q);
  layer2t<64, 2>(XB, 128, W + OFF_CW1T * 2, cb1, cg1, cn1, A0, PB, c, q, lane);
  __builtin_amdgcn_sched_barrier(0);
  layer2t<256, 1>(A0, 512, W + OFF_CW2T * 2, cb2, cg2, cn2, A1, PB, c, q, lane);
  __builtin_amdgcn_sched_barrier(0);
  {
    f32x4 v0[1], v1[1];
    run_small2<1>(A1, W + OFF_CW3T * 2, c, q, lane, v0, v1);
    const float b3 = cb3[0];
    if (c == 0) {
#pragma unroll
      for (int r = 0; r < 4; ++r) {
        const int g0 = base + q * 4 + r;
        const int g1 = base + 16 + q * 4 + r;
        const float nv0 = v0[0][r] + b3;
        const float nv1 = v1[0][r] + b3;
        out[(size_t)g0 * 20 + 19] = vst0[r];   // stash value; gae -> return
        out[(size_t)g1 * 20 + 19] = vst1[r];
        deltas[g0] = rewards[g0] + 0.99f * nv0 * masks[g0] - vst0[r];
        deltas[g1] = rewards[g1] + 0.99f * nv1 * masks[g1] - vst1[r];
      }
    }
  }
}

// ---------------------------------------------------------------------------
// GAE, wave-parallel: each wave owns a 512-elem chunk + 512-elem lookahead.
// Truncation: GL^512 ~ 2e-14. value stashed at out[:,19] -> returns.
__global__ __launch_bounds__(256) void gae_kernel(
    const float* __restrict__ deltas, const float* __restrict__ masks,
    float* __restrict__ out) {
  const int w = (blockIdx.x * blockDim.x + threadIdx.x) >> 6;  // 0..1023
  const int lane = threadIdx.x & 63;
  const int idx0 = w * 512 + lane * 16;

  float d[16], cf[16];
  if (idx0 < T_SZ) {
#pragma unroll
    for (int i = 0; i < 4; ++i) {
      *(float4*)(d + i * 4)  = *(const float4*)(deltas + idx0 + i * 4);
      *(float4*)(cf + i * 4) = *(const float4*)(masks + idx0 + i * 4);
    }
#pragma unroll
    for (int i = 0; i < 16; ++i) cf[i] *= GL;
  } else {
#pragma unroll
    for (int i = 0; i < 16; ++i) { d[i] = 0.f; cf[i] = 0.f; }
  }

  float A = 0.f, P = 1.f;
#pragma unroll
  for (int i = 15; i >= 0; --i) { A = d[i] + cf[i] * A; P *= cf[i]; }

  float As = A, Ps = P;
#pragma unroll
  for (int st = 1; st < 64; st <<= 1) {
    float An = __shfl_down(As, st, 64);
    float Pn = __shfl_down(Ps, st, 64);
    if (lane + st < 64) { As = As + Ps * An; Ps = Ps * Pn; }
  }
  float G = __shfl_down(As, 1, 64);
  if (lane == 63) G = 0.f;

  if (lane < 32) {
    float g = G;
#pragma unroll
    for (int i = 15; i >= 0; --i) {
      g = d[i] + cf[i] * g;
      const size_t j = (size_t)(idx0 + i);
      float val = out[j * 20 + 19];
      out[j * 20 + 18] = g;
      out[j * 20 + 19] = g + val;
    }
  }
}

// ---------------------------------------------------------------------------
extern "C" void kernel_launch(void* const* d_in, const int* in_sizes, int n_in,
                              void* d_out, int out_size, void* d_ws, size_t ws_size,
                              hipStream_t stream) {
  const float* states      = (const float*)d_in[0];
  const float* next_states = (const float*)d_in[1];
  const float* rewards     = (const float*)d_in[2];
  const float* masks       = (const float*)d_in[3];
  const float* aw1 = (const float*)d_in[4];
  const float* ab1 = (const float*)d_in[5];
  const float* ag1 = (const float*)d_in[6];
  const float* an1 = (const float*)d_in[7];
  const float* aw2 = (const float*)d_in[8];
  const float* ab2 = (const float*)d_in[9];
  const float* ag2 = (const float*)d_in[10];
  const float* an2 = (const float*)d_in[11];
  const float* aw3 = (const float*)d_in[12];
  const float* ab3 = (const float*)d_in[13];
  const float* cw1 = (const float*)d_in[14];
  const float* cb1 = (const float*)d_in[15];
  const float* cg1 = (const float*)d_in[16];
  const float* cn1 = (const float*)d_in[17];
  const float* cw2 = (const float*)d_in[18];
  const float* cb2 = (const float*)d_in[19];
  const float* cg2 = (const float*)d_in[20];
  const float* cn2 = (const float*)d_in[21];
  const float* cw3 = (const float*)d_in[22];
  const float* cb3 = (const float*)d_in[23];

  __hip_bfloat16* wbuf = (__hip_bfloat16*)d_ws;
  float* deltas = (float*)((char*)d_ws + OFF_DELTAS_BYTES);
  float* out = (float*)d_out;

  prep_weights<<<(W_ELEMS + 255) / 256, 256, 0, stream>>>(aw1, aw2, aw3, cw1, cw2, cw3, wbuf);
  mlp_kernel<<<T_SZ / 64, 128, 0, stream>>>(
      states, next_states, rewards, masks,
      ab1, ag1, an1, ab2, ag2, an2, ab3,
      cb1, cg1, cn1, cb2, cg2, cn2, cb3,
      wbuf, deltas, out);
  gae_kernel<<<256, 256, 0, stream>>>(deltas, masks, out);
}

// Round 16
// 788.166 us; speedup vs baseline: 1.4748x; 1.4748x over previous
//
#include <hip/hip_runtime.h>
#include <hip/hip_bf16.h>

// ============================================================================
// PPO agent fused forward (round 16):
//  r15: 1 wave/SIMD (LDS 40KB/wave + 140 VGPR both cap), ~60% stall. The
//  32-row dataflow can't reach 2/SIMD. This round: 16-row waves + r15's
//  machinery, tuned so BOTH caps pass at 2 waves/SIMD:
//   - per wave: A0 8KB + A1 8KB (stash/activations), X staged into idle A1.
//   - params staged ONCE per block into shared 12KB LDS (wave w stages LN
//     set w; one barrier). In-loop param reads = ds_read_b32.
//   - regs ~80 (acc 8 + s/ss 8 + temps) -> __launch_bounds__(256,2), 128 arch.
//   - LDS 4x16KB + 12KB = 76KB/block -> 2 blocks/CU = 8 waves/CU = 2/SIMD.
//   - per-layer __syncthreads keeps the 4 waves lockstep on the same weight
//     stream (L1 reuse; B-traffic doubled vs r15 by losing 2-tile pairing).
//  Same rounding points as r14/r15 -> absmax ~0.125.
// ============================================================================

#define T_SZ 524288
#define GL 0.9405f   // GAMMA*LAM

typedef __attribute__((ext_vector_type(8))) short bf16x8;   // 8 bf16 (4 VGPRs)
typedef __attribute__((ext_vector_type(4))) float f32x4;

// ws layout (bf16 elements); weights in ntile/fragment-major layout (r13)
#define OFF_AW1T 0        // 256x64
#define OFF_AW2T 16384    // 256x256
#define OFF_AW3T 81920    // 32x256 (rows >=18 zero)
#define OFF_CW1T 90112    // 256x64
#define OFF_CW2T 106496   // 256x256
#define OFF_CW3T 172032   // 16x256 (rows >=1 zero)
#define W_ELEMS  176128
#define OFF_DELTAS_BYTES 352256

// k = p*32 + h*16 + w -> pos = p*32 + w*2 + h (applied to A and B alike)
__device__ __forceinline__ int perm_k(int k) {
  return (k & ~31) | ((k & 15) << 1) | ((k >> 4) & 1);
}

__device__ __forceinline__ unsigned pack2(float a, float b) {
  __hip_bfloat162 h = __float22bfloat162_rn(float2{a, b});   // v_cvt_pk_bf16_f32
  union { __hip_bfloat162 h2; unsigned u; } x;
  x.h2 = h;
  return x.u;
}

__device__ __forceinline__ void unpack2(unsigned u, float& a, float& b) {
  union { unsigned u; float f; } x, y;
  x.u = u << 16; y.u = u & 0xFFFF0000u;
  a = x.f; b = y.f;
}

// ---------------------------------------------------------------------------
// stage X: 16 rows x 64 fp32 -> k-permuted swizzled bf16 LDS [16][128B]
__device__ __forceinline__ void stage_x(const float* __restrict__ src,
                                        char* XB, int c, int q) {
  const float* rp = src + (size_t)c * 64;
#pragma unroll
  for (int ks = 0; ks < 2; ++ks) {
    float4 a = *(const float4*)(rp + ks * 32 + 4 * q);
    float4 b = *(const float4*)(rp + ks * 32 + 4 * q + 16);
    unsigned u[4];
    u[0] = pack2(a.x, b.x); u[1] = pack2(a.y, b.y);
    u[2] = pack2(a.z, b.z); u[3] = pack2(a.w, b.w);
    *(uint4*)(XB + c * 128 + ((ks * 64 + q * 16) ^ ((c & 7) << 4))) = *(uint4*)u;
  }
}

// ---------------------------------------------------------------------------
// Linear(K->256)+bias+LN+ReLU for ONE 16-row tile, nt in even/odd pairs.
// A from LDS (astr bytes/row), B global fragment-major, params PF (LDS).
template<int K, int UNR>
__device__ __forceinline__ void layer1t(const char* A, int astr,
    const char* __restrict__ W, const float* PF, char* O,
    int c, int q, int lane) {
  constexpr int NK = K / 32;
  float s[4] = {0, 0, 0, 0}, ss[4] = {0, 0, 0, 0};
  const int sw = (c & 7) << 4;
#pragma unroll UNR
  for (int g = 0; g < 8; ++g) {          // nt pair (2g, 2g+1)
    const char* We = W + (size_t)(2 * g) * (K * 32);
    const char* Wo = We + (size_t)(K * 32);
    f32x4 e = {0.f, 0.f, 0.f, 0.f}, o = {0.f, 0.f, 0.f, 0.f};
#pragma unroll
    for (int ks = 0; ks < NK; ++ks) {
      bf16x8 be = *(const bf16x8*)(We + ks * 1024 + lane * 16);
      bf16x8 bo = *(const bf16x8*)(Wo + ks * 1024 + lane * 16);
      bf16x8 a = *(const bf16x8*)(A + (size_t)c * astr + ((ks * 64 + q * 16) ^ sw));
      e = __builtin_amdgcn_mfma_f32_16x16x32_bf16(a, be, e, 0, 0, 0);
      o = __builtin_amdgcn_mfma_f32_16x16x32_bf16(a, bo, o, 0, 0, 0);
    }
    const float bbe = PF[2 * g * 16 + c];        // ds_read_b32
    const float bbo = PF[(2 * g + 1) * 16 + c];
#pragma unroll
    for (int r = 0; r < 4; ++r) {
      float ve = e[r] + bbe, vo = o[r] + bbo;
      s[r] += ve + vo; ss[r] += ve * ve + vo * vo;
      const int rsw = ((q * 4 + r) & 7) << 4;
      *(unsigned*)(O + (q * 4 + r) * 512 + ((g * 64 + c * 4) ^ rsw)) = pack2(ve, vo);
    }
  }
  // stats over the 16 c-lanes (lane = q*16+c; xor m<16 flips c only)
#pragma unroll
  for (int m = 1; m < 16; m <<= 1) {
#pragma unroll
    for (int r = 0; r < 4; ++r) {
      s[r] += __shfl_xor(s[r], m, 64);
      ss[r] += __shfl_xor(ss[r], m, 64);
    }
  }
#pragma unroll
  for (int r = 0; r < 4; ++r) {
    float mu = s[r] * (1.f / 256.f);
    ss[r] = rsqrtf(ss[r] * (1.f / 256.f) - mu * mu + 1e-5f); s[r] = mu;
  }
  // pass-2: in-LDS RMW normalize+ReLU (lane-local stats, own rows)
#pragma unroll
  for (int p = 0; p < 8; ++p) {
    const float g0 = PF[256 + p * 32 + c],      b0v = PF[512 + p * 32 + c];
    const float g1 = PF[256 + p * 32 + 16 + c], b1v = PF[512 + p * 32 + 16 + c];
#pragma unroll
    for (int r = 0; r < 4; ++r) {
      unsigned* ap = (unsigned*)(O + (q * 4 + r) * 512 +
                                 ((p * 64 + c * 4) ^ (((q * 4 + r) & 7) << 4)));
      float v0, v1;
      unpack2(*ap, v0, v1);
      v0 = fmaxf((v0 - s[r]) * ss[r] * g0 + b0v, 0.f);
      v1 = fmaxf((v1 - s[r]) * ss[r] * g1 + b1v, 0.f);
      *ap = pack2(v0, v1);
    }
  }
}

// small final GEMM: NT ntiles, K=256, one 16-row tile, A from LDS (stride 512)
template<int NT>
__device__ __forceinline__ void run_small1(const char* A,
    const char* __restrict__ W, int c, int q, int lane, f32x4* o) {
  const int sw = (c & 7) << 4;
#pragma unroll
  for (int nt = 0; nt < NT; ++nt) o[nt] = (f32x4){0.f, 0.f, 0.f, 0.f};
#pragma unroll
  for (int nt = 0; nt < NT; ++nt) {
    const char* Wn = W + (size_t)nt * 8192;
#pragma unroll
    for (int ks = 0; ks < 8; ++ks) {
      bf16x8 b = *(const bf16x8*)(Wn + ks * 1024 + lane * 16);
      bf16x8 a = *(const bf16x8*)(A + (size_t)c * 512 + ((ks * 64 + q * 16) ^ sw));
      o[nt] = __builtin_amdgcn_mfma_f32_16x16x32_bf16(a, b, o[nt], 0, 0, 0);
    }
  }
}

__device__ __forceinline__ void softmax_write(f32x4* acc3,
    const float* __restrict__ ab3, float* __restrict__ out,
    int grow0, int c, int q) {
  float b0 = ab3[c];
  float b1 = (c < 2) ? ab3[16 + c] : 0.f;
#pragma unroll
  for (int r = 0; r < 4; ++r) {
    float x0 = acc3[0][r] + b0;
    float x1 = (c < 2) ? (acc3[1][r] + b1) : -1e30f;
    float mx = fmaxf(x0, x1);
#pragma unroll
    for (int m = 1; m < 16; m <<= 1) mx = fmaxf(mx, __shfl_xor(mx, m, 64));
    float e0 = __expf(x0 - mx);
    float e1 = (c < 2) ? __expf(x1 - mx) : 0.f;
    float sm = e0 + e1;
#pragma unroll
    for (int m = 1; m < 16; m <<= 1) sm += __shfl_xor(sm, m, 64);
    float inv = 1.f / sm;
    int gr = grow0 + q * 4 + r;
    out[(size_t)gr * 20 + c] = e0 * inv;
    if (c < 2) out[(size_t)gr * 20 + 16 + c] = e1 * inv;
  }
}

// ---------------------------------------------------------------------------
// prep: ntile/fragment-major (r13-r15, verified). (n,k) of [N][K]:
// nt=n>>4, cc=n&15; kp=perm_k(k): ks=kp>>5, qq=(kp&31)>>3, e=kp&7
// -> elem = MO + nt*(16*K) + ks*512 + (qq*16+cc)*8 + e.
__device__ __forceinline__ int frag_idx(int mo, int K, int n, int k) {
  const int kp = perm_k(k);
  const int nt = n >> 4, cc = n & 15;
  const int ks = kp >> 5, w = kp & 31, qq = w >> 3, e = w & 7;
  return mo + nt * (16 * K) + ks * 512 + (qq * 16 + cc) * 8 + e;
}

__global__ void prep_weights(const float* __restrict__ aw1, const float* __restrict__ aw2,
                             const float* __restrict__ aw3, const float* __restrict__ cw1,
                             const float* __restrict__ cw2, const float* __restrict__ cw3,
                             __hip_bfloat16* __restrict__ wb) {
  int i = blockIdx.x * 256 + threadIdx.x;
  if (i >= W_ELEMS) return;
  float v; int dst;
  if (i < OFF_AW2T)      { int j = i;            int n = j >> 6, k = j & 63;  v = aw1[k * 256 + n];                 dst = frag_idx(OFF_AW1T, 64,  n, k); }
  else if (i < OFF_AW3T) { int j = i - OFF_AW2T; int n = j >> 8, k = j & 255; v = aw2[k * 256 + n];                 dst = frag_idx(OFF_AW2T, 256, n, k); }
  else if (i < OFF_CW1T) { int j = i - OFF_AW3T; int n = j >> 8, k = j & 255; v = (n < 18) ? aw3[k * 18 + n] : 0.f; dst = frag_idx(OFF_AW3T, 256, n, k); }
  else if (i < OFF_CW2T) { int j = i - OFF_CW1T; int n = j >> 6, k = j & 63;  v = cw1[k * 256 + n];                 dst = frag_idx(OFF_CW1T, 64,  n, k); }
  else if (i < OFF_CW3T) { int j = i - OFF_CW2T; int n = j >> 8, k = j & 255; v = cw2[k * 256 + n];                 dst = frag_idx(OFF_CW2T, 256, n, k); }
  else                   { int j = i - OFF_CW3T; int n = j >> 8, k = j & 255; v = (n == 0) ? cw3[k] : 0.f;          dst = frag_idx(OFF_CW3T, 256, n, k); }
  wb[dst] = __float2bfloat16(v);
}

// ---------------------------------------------------------------------------
__global__ __launch_bounds__(256, 2) void mlp_kernel(
    const float* __restrict__ states, const float* __restrict__ next_states,
    const float* __restrict__ rewards, const float* __restrict__ masks,
    const float* __restrict__ ab1, const float* __restrict__ ag1, const float* __restrict__ an1,
    const float* __restrict__ ab2, const float* __restrict__ ag2, const float* __restrict__ an2,
    const float* __restrict__ ab3,
    const float* __restrict__ cb1, const float* __restrict__ cg1, const float* __restrict__ cn1,
    const float* __restrict__ cb2, const float* __restrict__ cg2, const float* __restrict__ cn2,
    const float* __restrict__ cb3,
    const __hip_bfloat16* __restrict__ wbuf,
    float* __restrict__ deltas, float* __restrict__ out) {
  __shared__ char PB[12288];          // 4 LN param sets (bias|gam|bet) x 256 f32
  __shared__ char WV[4][16384];       // per wave: A0 8KB | A1 8KB (XB in A1)
  const int tid = threadIdx.x;
  const int wave = tid >> 6, lane = tid & 63;
  const int c = lane & 15, q = lane >> 4;
  char* A0 = WV[wave];
  char* A1 = WV[wave] + 8192;
  const char* W = (const char*)wbuf;
  const int base = blockIdx.x * 64 + wave * 16;   // 16 timesteps per wave

  // ---- stage params: wave w stages LN set w (bias@0, gam@1024, bet@2048) ----
  {
    const float* bsrc = (wave == 0) ? ab1 : (wave == 1) ? ab2 : (wave == 2) ? cb1 : cb2;
    const float* gsrc = (wave == 0) ? ag1 : (wave == 1) ? ag2 : (wave == 2) ? cg1 : cg2;
    const float* nsrc = (wave == 0) ? an1 : (wave == 1) ? an2 : (wave == 2) ? cn1 : cn2;
    char* dst = PB + wave * 3072;
    *(float4*)(dst + lane * 16)        = *(const float4*)(bsrc + lane * 4);
    *(float4*)(dst + 1024 + lane * 16) = *(const float4*)(gsrc + lane * 4);
    *(float4*)(dst + 2048 + lane * 16) = *(const float4*)(nsrc + lane * 4);
  }
  __syncthreads();
  const float* PA1 = (const float*)(PB);
  const float* PA2 = (const float*)(PB + 3072);
  const float* PC1 = (const float*)(PB + 6144);
  const float* PC2 = (const float*)(PB + 9216);

  // ---- ACTOR(states) ----
  stage_x(states + (size_t)base * 64, A1, c, q);      // XB lives in A1
  layer1t<64, 2>(A1, 128, W + OFF_AW1T * 2, PA1, A0, c, q, lane);
  __syncthreads();
  layer1t<256, 1>(A0, 512, W + OFF_AW2T * 2, PA2, A1, c, q, lane);
  __syncthreads();
  {
    f32x4 p3[2];
    run_small1<2>(A1, W + OFF_AW3T * 2, c, q, lane, p3);
    softmax_write(p3, ab3, out, base, c, q);
  }
  __syncthreads();

  // ---- CRITIC(states) ----
  stage_x(states + (size_t)base * 64, A1, c, q);      // A1 consumed above
  layer1t<64, 2>(A1, 128, W + OFF_CW1T * 2, PC1, A0, c, q, lane);
  __syncthreads();
  layer1t<256, 1>(A0, 512, W + OFF_CW2T * 2, PC2, A1, c, q, lane);
  __syncthreads();
  float vst[4];
  {
    f32x4 v[1];
    run_small1<1>(A1, W + OFF_CW3T * 2, c, q, lane, v);
    const float b3 = cb3[0];
#pragma unroll
    for (int r = 0; r < 4; ++r) vst[r] = v[0][r] + b3;
  }
  __syncthreads();

  // ---- CRITIC(next_states) ----
  stage_x(next_states + (size_t)base * 64, A1, c, q);
  layer1t<64, 2>(A1, 128, W + OFF_CW1T * 2, PC1, A0, c, q, lane);
  __syncthreads();
  layer1t<256, 1>(A0, 512, W + OFF_CW2T * 2, PC2, A1, c, q, lane);
  __syncthreads();
  {
    f32x4 v[1];
    run_small1<1>(A1, W + OFF_CW3T * 2, c, q, lane, v);
    const float b3 = cb3[0];
    if (c == 0) {
#pragma unroll
      for (int r = 0; r < 4; ++r) {
        const int gr = base + q * 4 + r;
        const float nv = v[0][r] + b3;
        out[(size_t)gr * 20 + 19] = vst[r];   // stash value; gae -> return
        deltas[gr] = rewards[gr] + 0.99f * nv * masks[gr] - vst[r];
      }
    }
  }
}

// ---------------------------------------------------------------------------
// GAE, wave-parallel: each wave owns a 512-elem chunk + 512-elem lookahead.
// Truncation: GL^512 ~ 2e-14. value stashed at out[:,19] -> returns.
__global__ __launch_bounds__(256) void gae_kernel(
    const float* __restrict__ deltas, const float* __restrict__ masks,
    float* __restrict__ out) {
  const int w = (blockIdx.x * blockDim.x + threadIdx.x) >> 6;  // 0..1023
  const int lane = threadIdx.x & 63;
  const int idx0 = w * 512 + lane * 16;

  float d[16], cf[16];
  if (idx0 < T_SZ) {
#pragma unroll
    for (int i = 0; i < 4; ++i) {
      *(float4*)(d + i * 4)  = *(const float4*)(deltas + idx0 + i * 4);
      *(float4*)(cf + i * 4) = *(const float4*)(masks + idx0 + i * 4);
    }
#pragma unroll
    for (int i = 0; i < 16; ++i) cf[i] *= GL;
  } else {
#pragma unroll
    for (int i = 0; i < 16; ++i) { d[i] = 0.f; cf[i] = 0.f; }
  }

  float A = 0.f, P = 1.f;
#pragma unroll
  for (int i = 15; i >= 0; --i) { A = d[i] + cf[i] * A; P *= cf[i]; }

  float As = A, Ps = P;
#pragma unroll
  for (int st = 1; st < 64; st <<= 1) {
    float An = __shfl_down(As, st, 64);
    float Pn = __shfl_down(Ps, st, 64);
    if (lane + st < 64) { As = As + Ps * An; Ps = Ps * Pn; }
  }
  float G = __shfl_down(As, 1, 64);
  if (lane == 63) G = 0.f;

  if (lane < 32) {
    float g = G;
#pragma unroll
    for (int i = 15; i >= 0; --i) {
      g = d[i] + cf[i] * g;
      const size_t j = (size_t)(idx0 + i);
      float val = out[j * 20 + 19];
      out[j * 20 + 18] = g;
      out[j * 20 + 19] = g + val;
    }
  }
}

// ---------------------------------------------------------------------------
extern "C" void kernel_launch(void* const* d_in, const int* in_sizes, int n_in,
                              void* d_out, int out_size, void* d_ws, size_t ws_size,
                              hipStream_t stream) {
  const float* states      = (const float*)d_in[0];
  const float* next_states = (const float*)d_in[1];
  const float* rewards     = (const float*)d_in[2];
  const float* masks       = (const float*)d_in[3];
  const float* aw1 = (const float*)d_in[4];
  const float* ab1 = (const float*)d_in[5];
  const float* ag1 = (const float*)d_in[6];
  const float* an1 = (const float*)d_in[7];
  const float* aw2 = (const float*)d_in[8];
  const float* ab2 = (const float*)d_in[9];
  const float* ag2 = (const float*)d_in[10];
  const float* an2 = (const float*)d_in[11];
  const float* aw3 = (const float*)d_in[12];
  const float* ab3 = (const float*)d_in[13];
  const float* cw1 = (const float*)d_in[14];
  const float* cb1 = (const float*)d_in[15];
  const float* cg1 = (const float*)d_in[16];
  const float* cn1 = (const float*)d_in[17];
  const float* cw2 = (const float*)d_in[18];
  const float* cb2 = (const float*)d_in[19];
  const float* cg2 = (const float*)d_in[20];
  const float* cn2 = (const float*)d_in[21];
  const float* cw3 = (const float*)d_in[22];
  const float* cb3 = (const float*)d_in[23];

  __hip_bfloat16* wbuf = (__hip_bfloat16*)d_ws;
  float* deltas = (float*)((char*)d_ws + OFF_DELTAS_BYTES);
  float* out = (float*)d_out;

  prep_weights<<<(W_ELEMS + 255) / 256, 256, 0, stream>>>(aw1, aw2, aw3, cw1, cw2, cw3, wbuf);
  mlp_kernel<<<T_SZ / 64, 256, 0, stream>>>(
      states, next_states, rewards, masks,
      ab1, ag1, an1, ab2, ag2, an2, ab3,
      cb1, cg1, cn1, cb2, cg2, cn2, cb3,
      wbuf, deltas, out);
  gae_kernel<<<256, 256, 0, stream>>>(deltas, masks, out);
}

// Round 17
// 653.921 us; speedup vs baseline: 1.7776x; 1.2053x over previous
//
#include <hip/hip_runtime.h>
#include <hip/hip_bf16.h>

// ============================================================================
// PPO agent fused forward (round 17):
//  r16: 2 waves/SIMD, 88 VGPR, VALU-dominated (42% vs MFMA 12.8%). Fat:
//  per 256-layer, A-frags re-read from LDS 8x (64 ds_read_b128) and a full
//  pass-2 LDS RMW normalize (64 RMW + ~320 VALU).
//  This round (r8's machinery in the viable occupancy box):
//   - A-frags hoisted to regs (af[8], 32 VGPRs) once per layer.
//   - pass-2 folded into next-layer frag construction: stats broadcast via
//     srcLane shuffle (r8-verified), normalize+ReLU in regs, no write-back.
//   - LDS: 8KB stash/wave + 12KB params = 44KB/block; cap moves to VGPR
//     (~115 arch < 128 at __launch_bounds__(256,2) -> still 2 waves/SIMD).
//   - xf stays live actor->critic (one X reload saved).
//   - B fragment-major/coalesced + lockstep barriers (r16 wins kept).
//  Same rounding points as r14-r16 -> absmax ~0.125.
// ============================================================================

#define T_SZ 524288
#define GL 0.9405f   // GAMMA*LAM

typedef __attribute__((ext_vector_type(8))) short bf16x8;   // 8 bf16 (4 VGPRs)
typedef __attribute__((ext_vector_type(4))) float f32x4;

// ws layout (bf16 elements); weights in ntile/fragment-major layout (r13)
#define OFF_AW1T 0        // 256x64
#define OFF_AW2T 16384    // 256x256
#define OFF_AW3T 81920    // 32x256 (rows >=18 zero)
#define OFF_CW1T 90112    // 256x64
#define OFF_CW2T 106496   // 256x256
#define OFF_CW3T 172032   // 16x256 (rows >=1 zero)
#define W_ELEMS  176128
#define OFF_DELTAS_BYTES 352256

// k = p*32 + h*16 + w -> pos = p*32 + w*2 + h (applied to A and B alike)
__device__ __forceinline__ int perm_k(int k) {
  return (k & ~31) | ((k & 15) << 1) | ((k >> 4) & 1);
}

__device__ __forceinline__ unsigned pack2(float a, float b) {
  __hip_bfloat162 h = __float22bfloat162_rn(float2{a, b});   // v_cvt_pk_bf16_f32
  union { __hip_bfloat162 h2; unsigned u; } x;
  x.h2 = h;
  return x.u;
}

__device__ __forceinline__ void unpack2(unsigned u, float& a, float& b) {
  union { unsigned u; float f; } x, y;
  x.u = u << 16; y.u = u & 0xFFFF0000u;
  a = x.f; b = y.f;
}

// ACT stash accessor (stride 512B, 16B-granular XOR on row&7)
__device__ __forceinline__ void* act_at(void* base, int row, int colByte) {
  return (char*)base + row * 512 + (colByte ^ ((row & 7) << 4));
}

// ---------------------------------------------------------------------------
// X tile (16 rows x 64 fp32) -> 2 k-permuted bf16x8 frags per lane (no LDS).
__device__ __forceinline__ void load_x_frags(const float* __restrict__ src,
                                             int c, int q, bf16x8* xf) {
  const float* rp = src + (size_t)c * 64;
#pragma unroll
  for (int ks = 0; ks < 2; ++ks) {
    float4 a = *(const float4*)(rp + ks * 32 + 4 * q);
    float4 b = *(const float4*)(rp + ks * 32 + 4 * q + 16);
    unsigned u[4];
    u[0] = pack2(a.x, b.x); u[1] = pack2(a.y, b.y);
    u[2] = pack2(a.z, b.z); u[3] = pack2(a.w, b.w);
    xf[ks] = *(bf16x8*)u;
  }
}

// ---------------------------------------------------------------------------
// Linear(K->256)+bias+LN+ReLU. A-frags in regs (af[K/32]); B global
// fragment-major; params PF (LDS). Pass-1: per nt-pair MFMA -> bias -> s/ss
// -> pre-LN bf16 pair stash. Stats + srcLane broadcast; frag-build in regs
// (normalize+ReLU) -> of[8]. of may alias af.
template<int K, int UNR>
__device__ __forceinline__ void layer_reg(const bf16x8* af,
    const char* __restrict__ W, const float* PF, char* ACT,
    int c, int q, int lane, bf16x8* of) {
  constexpr int NK = K / 32;
  float s[4] = {0, 0, 0, 0}, ss[4] = {0, 0, 0, 0};
#pragma unroll UNR
  for (int g = 0; g < 8; ++g) {          // nt pair (2g, 2g+1)
    const char* We = W + (size_t)(2 * g) * (K * 32);
    const char* Wo = We + (size_t)(K * 32);
    f32x4 e = {0.f, 0.f, 0.f, 0.f}, o = {0.f, 0.f, 0.f, 0.f};
#pragma unroll
    for (int ks = 0; ks < NK; ++ks) {
      bf16x8 be = *(const bf16x8*)(We + ks * 1024 + lane * 16);
      bf16x8 bo = *(const bf16x8*)(Wo + ks * 1024 + lane * 16);
      e = __builtin_amdgcn_mfma_f32_16x16x32_bf16(af[ks], be, e, 0, 0, 0);
      o = __builtin_amdgcn_mfma_f32_16x16x32_bf16(af[ks], bo, o, 0, 0, 0);
    }
    const float bbe = PF[2 * g * 16 + c];        // ds_read_b32
    const float bbo = PF[(2 * g + 1) * 16 + c];
#pragma unroll
    for (int r = 0; r < 4; ++r) {
      float ve = e[r] + bbe, vo = o[r] + bbo;
      s[r] += ve + vo; ss[r] += ve * ve + vo * vo;
      *(unsigned*)act_at(ACT, q * 4 + r, g * 64 + c * 4) = pack2(ve, vo);
    }
  }
  // stats over the 16 c-lanes (lane = q*16+c; xor m<16 flips c only)
#pragma unroll
  for (int m = 1; m < 16; m <<= 1) {
#pragma unroll
    for (int r = 0; r < 4; ++r) {
      s[r] += __shfl_xor(s[r], m, 64);
      ss[r] += __shfl_xor(ss[r], m, 64);
    }
  }
  float mean[4], rs[4];
#pragma unroll
  for (int r = 0; r < 4; ++r) {
    mean[r] = s[r] * (1.f / 256.f);
    float var = ss[r] * (1.f / 256.f) - mean[r] * mean[r];
    rs[r] = rsqrtf(var + 1e-5f);
  }
  // broadcast row-c stats: row c's stats live in lane q'=c>>2, slot r=c&3
  const int srcLane = ((c >> 2) << 4) + c;
  float mb[4], rb[4];
#pragma unroll
  for (int r = 0; r < 4; ++r) {
    mb[r] = __shfl(mean[r], srcLane, 64);
    rb[r] = __shfl(rs[r],   srcLane, 64);
  }
  const float m01 = (c & 1) ? mb[1] : mb[0], m23 = (c & 1) ? mb[3] : mb[2];
  const float r01 = (c & 1) ? rb[1] : rb[0], r23 = (c & 1) ? rb[3] : rb[2];
  const float mc = (c & 2) ? m23 : m01;
  const float rc = (c & 2) ? r23 : r01;
  // frag-build: read pre-LN pairs for row c, normalize+ReLU in regs -> of
  const float* GM = PF + 256;
  const float* BT = PF + 512;
#pragma unroll
  for (int ks = 0; ks < 8; ++ks) {
    uint4 dv = *(const uint4*)act_at(ACT, c, ks * 64 + q * 16);
    unsigned w[4];
    const unsigned* dp = (const unsigned*)&dv;
#pragma unroll
    for (int i = 0; i < 4; ++i) {
      const int n0 = ks * 32 + q * 4 + i;
      float v0, v1;
      unpack2(dp[i], v0, v1);
      float w0 = fmaxf((v0 - mc) * rc * GM[n0]      + BT[n0],      0.f);
      float w1 = fmaxf((v1 - mc) * rc * GM[n0 + 16] + BT[n0 + 16], 0.f);
      w[i] = pack2(w0, w1);
    }
    of[ks] = *(bf16x8*)w;
  }
}

// small final GEMM: NT ntiles, K=256, A-frags in regs, B fragment-major
template<int NT>
__device__ __forceinline__ void run_small_reg(const bf16x8* af,
    const char* __restrict__ W, int lane, f32x4* o) {
#pragma unroll
  for (int nt = 0; nt < NT; ++nt) o[nt] = (f32x4){0.f, 0.f, 0.f, 0.f};
#pragma unroll
  for (int nt = 0; nt < NT; ++nt) {
    const char* Wn = W + (size_t)nt * 8192;
#pragma unroll
    for (int ks = 0; ks < 8; ++ks) {
      bf16x8 b = *(const bf16x8*)(Wn + ks * 1024 + lane * 16);
      o[nt] = __builtin_amdgcn_mfma_f32_16x16x32_bf16(af[ks], b, o[nt], 0, 0, 0);
    }
  }
}

__device__ __forceinline__ void softmax_write(f32x4* acc3,
    const float* __restrict__ ab3, float* __restrict__ out,
    int grow0, int c, int q) {
  float b0 = ab3[c];
  float b1 = (c < 2) ? ab3[16 + c] : 0.f;
#pragma unroll
  for (int r = 0; r < 4; ++r) {
    float x0 = acc3[0][r] + b0;
    float x1 = (c < 2) ? (acc3[1][r] + b1) : -1e30f;
    float mx = fmaxf(x0, x1);
#pragma unroll
    for (int m = 1; m < 16; m <<= 1) mx = fmaxf(mx, __shfl_xor(mx, m, 64));
    float e0 = __expf(x0 - mx);
    float e1 = (c < 2) ? __expf(x1 - mx) : 0.f;
    float sm = e0 + e1;
#pragma unroll
    for (int m = 1; m < 16; m <<= 1) sm += __shfl_xor(sm, m, 64);
    float inv = 1.f / sm;
    int gr = grow0 + q * 4 + r;
    out[(size_t)gr * 20 + c] = e0 * inv;
    if (c < 2) out[(size_t)gr * 20 + 16 + c] = e1 * inv;
  }
}

// ---------------------------------------------------------------------------
// prep: ntile/fragment-major (r13-r16, verified). (n,k) of [N][K]:
// nt=n>>4, cc=n&15; kp=perm_k(k): ks=kp>>5, qq=(kp&31)>>3, e=kp&7
// -> elem = MO + nt*(16*K) + ks*512 + (qq*16+cc)*8 + e.
__device__ __forceinline__ int frag_idx(int mo, int K, int n, int k) {
  const int kp = perm_k(k);
  const int nt = n >> 4, cc = n & 15;
  const int ks = kp >> 5, w = kp & 31, qq = w >> 3, e = w & 7;
  return mo + nt * (16 * K) + ks * 512 + (qq * 16 + cc) * 8 + e;
}

__global__ void prep_weights(const float* __restrict__ aw1, const float* __restrict__ aw2,
                             const float* __restrict__ aw3, const float* __restrict__ cw1,
                             const float* __restrict__ cw2, const float* __restrict__ cw3,
                             __hip_bfloat16* __restrict__ wb) {
  int i = blockIdx.x * 256 + threadIdx.x;
  if (i >= W_ELEMS) return;
  float v; int dst;
  if (i < OFF_AW2T)      { int j = i;            int n = j >> 6, k = j & 63;  v = aw1[k * 256 + n];                 dst = frag_idx(OFF_AW1T, 64,  n, k); }
  else if (i < OFF_AW3T) { int j = i - OFF_AW2T; int n = j >> 8, k = j & 255; v = aw2[k * 256 + n];                 dst = frag_idx(OFF_AW2T, 256, n, k); }
  else if (i < OFF_CW1T) { int j = i - OFF_AW3T; int n = j >> 8, k = j & 255; v = (n < 18) ? aw3[k * 18 + n] : 0.f; dst = frag_idx(OFF_AW3T, 256, n, k); }
  else if (i < OFF_CW2T) { int j = i - OFF_CW1T; int n = j >> 6, k = j & 63;  v = cw1[k * 256 + n];                 dst = frag_idx(OFF_CW1T, 64,  n, k); }
  else if (i < OFF_CW3T) { int j = i - OFF_CW2T; int n = j >> 8, k = j & 255; v = cw2[k * 256 + n];                 dst = frag_idx(OFF_CW2T, 256, n, k); }
  else                   { int j = i - OFF_CW3T; int n = j >> 8, k = j & 255; v = (n == 0) ? cw3[k] : 0.f;          dst = frag_idx(OFF_CW3T, 256, n, k); }
  wb[dst] = __float2bfloat16(v);
}

// ---------------------------------------------------------------------------
__global__ __launch_bounds__(256, 2) void mlp_kernel(
    const float* __restrict__ states, const float* __restrict__ next_states,
    const float* __restrict__ rewards, const float* __restrict__ masks,
    const float* __restrict__ ab1, const float* __restrict__ ag1, const float* __restrict__ an1,
    const float* __restrict__ ab2, const float* __restrict__ ag2, const float* __restrict__ an2,
    const float* __restrict__ ab3,
    const float* __restrict__ cb1, const float* __restrict__ cg1, const float* __restrict__ cn1,
    const float* __restrict__ cb2, const float* __restrict__ cg2, const float* __restrict__ cn2,
    const float* __restrict__ cb3,
    const __hip_bfloat16* __restrict__ wbuf,
    float* __restrict__ deltas, float* __restrict__ out) {
  __shared__ char PB[12288];          // 4 LN param sets (bias|gam|bet) x 256 f32
  __shared__ char WV[4][8192];        // per-wave pre-LN stash
  const int tid = threadIdx.x;
  const int wave = tid >> 6, lane = tid & 63;
  const int c = lane & 15, q = lane >> 4;
  char* ACT = WV[wave];
  const char* W = (const char*)wbuf;
  const int base = blockIdx.x * 64 + wave * 16;   // 16 timesteps per wave

  // ---- stage params: wave w stages LN set w (bias@0, gam@1024, bet@2048) ----
  {
    const float* bsrc = (wave == 0) ? ab1 : (wave == 1) ? ab2 : (wave == 2) ? cb1 : cb2;
    const float* gsrc = (wave == 0) ? ag1 : (wave == 1) ? ag2 : (wave == 2) ? cg1 : cg2;
    const float* nsrc = (wave == 0) ? an1 : (wave == 1) ? an2 : (wave == 2) ? cn1 : cn2;
    char* dst = PB + wave * 3072;
    *(float4*)(dst + lane * 16)        = *(const float4*)(bsrc + lane * 4);
    *(float4*)(dst + 1024 + lane * 16) = *(const float4*)(gsrc + lane * 4);
    *(float4*)(dst + 2048 + lane * 16) = *(const float4*)(nsrc + lane * 4);
  }
  __syncthreads();
  const float* PA1 = (const float*)(PB);
  const float* PA2 = (const float*)(PB + 3072);
  const float* PC1 = (const float*)(PB + 6144);
  const float* PC2 = (const float*)(PB + 9216);

  bf16x8 xf[2], af[8];

  // ---- X(states) -> regs (kept live across actor + critic) ----
  load_x_frags(states + (size_t)base * 64, c, q, xf);

  // ---- ACTOR(states) ----
  layer_reg<64, 2>(xf, W + OFF_AW1T * 2, PA1, ACT, c, q, lane, af);
  __syncthreads();
  layer_reg<256, 1>(af, W + OFF_AW2T * 2, PA2, ACT, c, q, lane, af);
  __syncthreads();
  {
    f32x4 p3[2];
    run_small_reg<2>(af, W + OFF_AW3T * 2, lane, p3);
    softmax_write(p3, ab3, out, base, c, q);
  }
  __syncthreads();

  // ---- CRITIC(states) ---- (xf still live)
  layer_reg<64, 2>(xf, W + OFF_CW1T * 2, PC1, ACT, c, q, lane, af);
  __syncthreads();
  layer_reg<256, 1>(af, W + OFF_CW2T * 2, PC2, ACT, c, q, lane, af);
  __syncthreads();
  float vst[4];
  {
    f32x4 v[1];
    run_small_reg<1>(af, W + OFF_CW3T * 2, lane, v);
    const float b3 = cb3[0];
#pragma unroll
    for (int r = 0; r < 4; ++r) vst[r] = v[0][r] + b3;
  }
  __syncthreads();

  // ---- CRITIC(next_states) ----
  load_x_frags(next_states + (size_t)base * 64, c, q, xf);
  layer_reg<64, 2>(xf, W + OFF_CW1T * 2, PC1, ACT, c, q, lane, af);
  __syncthreads();
  layer_reg<256, 1>(af, W + OFF_CW2T * 2, PC2, ACT, c, q, lane, af);
  __syncthreads();
  {
    f32x4 v[1];
    run_small_reg<1>(af, W + OFF_CW3T * 2, lane, v);
    const float b3 = cb3[0];
    if (c == 0) {
#pragma unroll
      for (int r = 0; r < 4; ++r) {
        const int gr = base + q * 4 + r;
        const float nv = v[0][r] + b3;
        out[(size_t)gr * 20 + 19] = vst[r];   // stash value; gae -> return
        deltas[gr] = rewards[gr] + 0.99f * nv * masks[gr] - vst[r];
      }
    }
  }
}

// ---------------------------------------------------------------------------
// GAE, wave-parallel: each wave owns a 512-elem chunk + 512-elem lookahead.
// Truncation: GL^512 ~ 2e-14. value stashed at out[:,19] -> returns.
__global__ __launch_bounds__(256) void gae_kernel(
    const float* __restrict__ deltas, const float* __restrict__ masks,
    float* __restrict__ out) {
  const int w = (blockIdx.x * blockDim.x + threadIdx.x) >> 6;  // 0..1023
  const int lane = threadIdx.x & 63;
  const int idx0 = w * 512 + lane * 16;

  float d[16], cf[16];
  if (idx0 < T_SZ) {
#pragma unroll
    for (int i = 0; i < 4; ++i) {
      *(float4*)(d + i * 4)  = *(const float4*)(deltas + idx0 + i * 4);
      *(float4*)(cf + i * 4) = *(const float4*)(masks + idx0 + i * 4);
    }
#pragma unroll
    for (int i = 0; i < 16; ++i) cf[i] *= GL;
  } else {
#pragma unroll
    for (int i = 0; i < 16; ++i) { d[i] = 0.f; cf[i] = 0.f; }
  }

  float A = 0.f, P = 1.f;
#pragma unroll
  for (int i = 15; i >= 0; --i) { A = d[i] + cf[i] * A; P *= cf[i]; }

  float As = A, Ps = P;
#pragma unroll
  for (int st = 1; st < 64; st <<= 1) {
    float An = __shfl_down(As, st, 64);
    float Pn = __shfl_down(Ps, st, 64);
    if (lane + st < 64) { As = As + Ps * An; Ps = Ps * Pn; }
  }
  float G = __shfl_down(As, 1, 64);
  if (lane == 63) G = 0.f;

  if (lane < 32) {
    float g = G;
#pragma unroll
    for (int i = 15; i >= 0; --i) {
      g = d[i] + cf[i] * g;
      const size_t j = (size_t)(idx0 + i);
      float val = out[j * 20 + 19];
      out[j * 20 + 18] = g;
      out[j * 20 + 19] = g + val;
    }
  }
}

// ---------------------------------------------------------------------------
extern "C" void kernel_launch(void* const* d_in, const int* in_sizes, int n_in,
                              void* d_out, int out_size, void* d_ws, size_t ws_size,
                              hipStream_t stream) {
  const float* states      = (const float*)d_in[0];
  const float* next_states = (const float*)d_in[1];
  const float* rewards     = (const float*)d_in[2];
  const float* masks       = (const float*)d_in[3];
  const float* aw1 = (const float*)d_in[4];
  const float* ab1 = (const float*)d_in[5];
  const float* ag1 = (const float*)d_in[6];
  const float* an1 = (const float*)d_in[7];
  const float* aw2 = (const float*)d_in[8];
  const float* ab2 = (const float*)d_in[9];
  const float* ag2 = (const float*)d_in[10];
  const float* an2 = (const float*)d_in[11];
  const float* aw3 = (const float*)d_in[12];
  const float* ab3 = (const float*)d_in[13];
  const float* cw1 = (const float*)d_in[14];
  const float* cb1 = (const float*)d_in[15];
  const float* cg1 = (const float*)d_in[16];
  const float* cn1 = (const float*)d_in[17];
  const float* cw2 = (const float*)d_in[18];
  const float* cb2 = (const float*)d_in[19];
  const float* cg2 = (const float*)d_in[20];
  const float* cn2 = (const float*)d_in[21];
  const float* cw3 = (const float*)d_in[22];
  const float* cb3 = (const float*)d_in[23];

  __hip_bfloat16* wbuf = (__hip_bfloat16*)d_ws;
  float* deltas = (float*)((char*)d_ws + OFF_DELTAS_BYTES);
  float* out = (float*)d_out;

  prep_weights<<<(W_ELEMS + 255) / 256, 256, 0, stream>>>(aw1, aw2, aw3, cw1, cw2, cw3, wbuf);
  mlp_kernel<<<T_SZ / 64, 256, 0, stream>>>(
      states, next_states, rewards, masks,
      ab1, ag1, an1, ab2, ag2, an2, ab3,
      cb1, cg1, cn1, cb2, cg2, cn2, cb3,
      wbuf, deltas, out);
  gae_kernel<<<256, 256, 0, stream>>>(deltas, masks, out);
}

// Round 18
// 641.953 us; speedup vs baseline: 1.8107x; 1.0186x over previous
//
#include <hip/hip_runtime.h>
#include <hip/hip_bf16.h>

// ============================================================================
// PPO agent fused forward (round 18):
//  r17: 654us, issue-bound (VALU 49% + MFMA 15% + LDS ~10% ~= 75% issue), 3
//  waves/SIMD jointly capped by LDS(44KB) and VGPR shadow(80->160 unified).
//  More occupancy impossible (arch<=64 spills, r8). This round: instruction
//  diet only.
//   - frag-build: (v-mc)*rc*g+b -> fma(fma(v,rc,-mcr),g,b), mcr=mc*rc hoisted
//     (saves 1 VALU/element, ~8% of VALU).
//   - g-loop unroll: 256-layers UNR 1->2, 64-layers 2->4 (loop overhead cut;
//     VGPR headroom 80->~90, WRITE_SIZE is the spill canary).
//  Everything else identical to r17. absmax ~0.125.
// ============================================================================

#define T_SZ 524288
#define GL 0.9405f   // GAMMA*LAM

typedef __attribute__((ext_vector_type(8))) short bf16x8;   // 8 bf16 (4 VGPRs)
typedef __attribute__((ext_vector_type(4))) float f32x4;

// ws layout (bf16 elements); weights in ntile/fragment-major layout (r13)
#define OFF_AW1T 0        // 256x64
#define OFF_AW2T 16384    // 256x256
#define OFF_AW3T 81920    // 32x256 (rows >=18 zero)
#define OFF_CW1T 90112    // 256x64
#define OFF_CW2T 106496   // 256x256
#define OFF_CW3T 172032   // 16x256 (rows >=1 zero)
#define W_ELEMS  176128
#define OFF_DELTAS_BYTES 352256

// k = p*32 + h*16 + w -> pos = p*32 + w*2 + h (applied to A and B alike)
__device__ __forceinline__ int perm_k(int k) {
  return (k & ~31) | ((k & 15) << 1) | ((k >> 4) & 1);
}

__device__ __forceinline__ unsigned pack2(float a, float b) {
  __hip_bfloat162 h = __float22bfloat162_rn(float2{a, b});   // v_cvt_pk_bf16_f32
  union { __hip_bfloat162 h2; unsigned u; } x;
  x.h2 = h;
  return x.u;
}

__device__ __forceinline__ void unpack2(unsigned u, float& a, float& b) {
  union { unsigned u; float f; } x, y;
  x.u = u << 16; y.u = u & 0xFFFF0000u;
  a = x.f; b = y.f;
}

// ACT stash accessor (stride 512B, 16B-granular XOR on row&7)
__device__ __forceinline__ void* act_at(void* base, int row, int colByte) {
  return (char*)base + row * 512 + (colByte ^ ((row & 7) << 4));
}

// ---------------------------------------------------------------------------
// X tile (16 rows x 64 fp32) -> 2 k-permuted bf16x8 frags per lane (no LDS).
__device__ __forceinline__ void load_x_frags(const float* __restrict__ src,
                                             int c, int q, bf16x8* xf) {
  const float* rp = src + (size_t)c * 64;
#pragma unroll
  for (int ks = 0; ks < 2; ++ks) {
    float4 a = *(const float4*)(rp + ks * 32 + 4 * q);
    float4 b = *(const float4*)(rp + ks * 32 + 4 * q + 16);
    unsigned u[4];
    u[0] = pack2(a.x, b.x); u[1] = pack2(a.y, b.y);
    u[2] = pack2(a.z, b.z); u[3] = pack2(a.w, b.w);
    xf[ks] = *(bf16x8*)u;
  }
}

// ---------------------------------------------------------------------------
// Linear(K->256)+bias+LN+ReLU. A-frags in regs (af[K/32]); B global
// fragment-major; params PF (LDS). Pass-1: per nt-pair MFMA -> bias -> s/ss
// -> pre-LN bf16 pair stash. Stats + srcLane broadcast; frag-build in regs
// (normalize+ReLU, 2xfma form) -> of[8]. of may alias af.
template<int K, int UNR>
__device__ __forceinline__ void layer_reg(const bf16x8* af,
    const char* __restrict__ W, const float* PF, char* ACT,
    int c, int q, int lane, bf16x8* of) {
  constexpr int NK = K / 32;
  float s[4] = {0, 0, 0, 0}, ss[4] = {0, 0, 0, 0};
#pragma unroll UNR
  for (int g = 0; g < 8; ++g) {          // nt pair (2g, 2g+1)
    const char* We = W + (size_t)(2 * g) * (K * 32);
    const char* Wo = We + (size_t)(K * 32);
    f32x4 e = {0.f, 0.f, 0.f, 0.f}, o = {0.f, 0.f, 0.f, 0.f};
#pragma unroll
    for (int ks = 0; ks < NK; ++ks) {
      bf16x8 be = *(const bf16x8*)(We + ks * 1024 + lane * 16);
      bf16x8 bo = *(const bf16x8*)(Wo + ks * 1024 + lane * 16);
      e = __builtin_amdgcn_mfma_f32_16x16x32_bf16(af[ks], be, e, 0, 0, 0);
      o = __builtin_amdgcn_mfma_f32_16x16x32_bf16(af[ks], bo, o, 0, 0, 0);
    }
    const float bbe = PF[2 * g * 16 + c];        // ds_read_b32
    const float bbo = PF[(2 * g + 1) * 16 + c];
#pragma unroll
    for (int r = 0; r < 4; ++r) {
      float ve = e[r] + bbe, vo = o[r] + bbo;
      s[r] += ve + vo; ss[r] += ve * ve + vo * vo;
      *(unsigned*)act_at(ACT, q * 4 + r, g * 64 + c * 4) = pack2(ve, vo);
    }
  }
  // stats over the 16 c-lanes (lane = q*16+c; xor m<16 flips c only)
#pragma unroll
  for (int m = 1; m < 16; m <<= 1) {
#pragma unroll
    for (int r = 0; r < 4; ++r) {
      s[r] += __shfl_xor(s[r], m, 64);
      ss[r] += __shfl_xor(ss[r], m, 64);
    }
  }
  float mean[4], rs[4];
#pragma unroll
  for (int r = 0; r < 4; ++r) {
    mean[r] = s[r] * (1.f / 256.f);
    float var = ss[r] * (1.f / 256.f) - mean[r] * mean[r];
    rs[r] = rsqrtf(var + 1e-5f);
  }
  // broadcast row-c stats: row c's stats live in lane q'=c>>2, slot r=c&3
  const int srcLane = ((c >> 2) << 4) + c;
  float mb[4], rb[4];
#pragma unroll
  for (int r = 0; r < 4; ++r) {
    mb[r] = __shfl(mean[r], srcLane, 64);
    rb[r] = __shfl(rs[r],   srcLane, 64);
  }
  const float m01 = (c & 1) ? mb[1] : mb[0], m23 = (c & 1) ? mb[3] : mb[2];
  const float r01 = (c & 1) ? rb[1] : rb[0], r23 = (c & 1) ? rb[3] : rb[2];
  const float mc = (c & 2) ? m23 : m01;
  const float rc = (c & 2) ? r23 : r01;
  const float mcr = -mc * rc;            // hoisted: (v-mc)*rc = fma(v, rc, mcr)
  // frag-build: read pre-LN pairs for row c, normalize+ReLU in regs -> of
  const float* GM = PF + 256;
  const float* BT = PF + 512;
#pragma unroll
  for (int ks = 0; ks < 8; ++ks) {
    uint4 dv = *(const uint4*)act_at(ACT, c, ks * 64 + q * 16);
    unsigned w[4];
    const unsigned* dp = (const unsigned*)&dv;
#pragma unroll
    for (int i = 0; i < 4; ++i) {
      const int n0 = ks * 32 + q * 4 + i;
      float v0, v1;
      unpack2(dp[i], v0, v1);
      float w0 = fmaxf(fmaf(fmaf(v0, rc, mcr), GM[n0],      BT[n0]),      0.f);
      float w1 = fmaxf(fmaf(fmaf(v1, rc, mcr), GM[n0 + 16], BT[n0 + 16]), 0.f);
      w[i] = pack2(w0, w1);
    }
    of[ks] = *(bf16x8*)w;
  }
}

// small final GEMM: NT ntiles, K=256, A-frags in regs, B fragment-major
template<int NT>
__device__ __forceinline__ void run_small_reg(const bf16x8* af,
    const char* __restrict__ W, int lane, f32x4* o) {
#pragma unroll
  for (int nt = 0; nt < NT; ++nt) o[nt] = (f32x4){0.f, 0.f, 0.f, 0.f};
#pragma unroll
  for (int nt = 0; nt < NT; ++nt) {
    const char* Wn = W + (size_t)nt * 8192;
#pragma unroll
    for (int ks = 0; ks < 8; ++ks) {
      bf16x8 b = *(const bf16x8*)(Wn + ks * 1024 + lane * 16);
      o[nt] = __builtin_amdgcn_mfma_f32_16x16x32_bf16(af[ks], b, o[nt], 0, 0, 0);
    }
  }
}

__device__ __forceinline__ void softmax_write(f32x4* acc3,
    const float* __restrict__ ab3, float* __restrict__ out,
    int grow0, int c, int q) {
  float b0 = ab3[c];
  float b1 = (c < 2) ? ab3[16 + c] : 0.f;
#pragma unroll
  for (int r = 0; r < 4; ++r) {
    float x0 = acc3[0][r] + b0;
    float x1 = (c < 2) ? (acc3[1][r] + b1) : -1e30f;
    float mx = fmaxf(x0, x1);
#pragma unroll
    for (int m = 1; m < 16; m <<= 1) mx = fmaxf(mx, __shfl_xor(mx, m, 64));
    float e0 = __expf(x0 - mx);
    float e1 = (c < 2) ? __expf(x1 - mx) : 0.f;
    float sm = e0 + e1;
#pragma unroll
    for (int m = 1; m < 16; m <<= 1) sm += __shfl_xor(sm, m, 64);
    float inv = 1.f / sm;
    int gr = grow0 + q * 4 + r;
    out[(size_t)gr * 20 + c] = e0 * inv;
    if (c < 2) out[(size_t)gr * 20 + 16 + c] = e1 * inv;
  }
}

// ---------------------------------------------------------------------------
// prep: ntile/fragment-major (r13-r17, verified). (n,k) of [N][K]:
// nt=n>>4, cc=n&15; kp=perm_k(k): ks=kp>>5, qq=(kp&31)>>3, e=kp&7
// -> elem = MO + nt*(16*K) + ks*512 + (qq*16+cc)*8 + e.
__device__ __forceinline__ int frag_idx(int mo, int K, int n, int k) {
  const int kp = perm_k(k);
  const int nt = n >> 4, cc = n & 15;
  const int ks = kp >> 5, w = kp & 31, qq = w >> 3, e = w & 7;
  return mo + nt * (16 * K) + ks * 512 + (qq * 16 + cc) * 8 + e;
}

__global__ void prep_weights(const float* __restrict__ aw1, const float* __restrict__ aw2,
                             const float* __restrict__ aw3, const float* __restrict__ cw1,
                             const float* __restrict__ cw2, const float* __restrict__ cw3,
                             __hip_bfloat16* __restrict__ wb) {
  int i = blockIdx.x * 256 + threadIdx.x;
  if (i >= W_ELEMS) return;
  float v; int dst;
  if (i < OFF_AW2T)      { int j = i;            int n = j >> 6, k = j & 63;  v = aw1[k * 256 + n];                 dst = frag_idx(OFF_AW1T, 64,  n, k); }
  else if (i < OFF_AW3T) { int j = i - OFF_AW2T; int n = j >> 8, k = j & 255; v = aw2[k * 256 + n];                 dst = frag_idx(OFF_AW2T, 256, n, k); }
  else if (i < OFF_CW1T) { int j = i - OFF_AW3T; int n = j >> 8, k = j & 255; v = (n < 18) ? aw3[k * 18 + n] : 0.f; dst = frag_idx(OFF_AW3T, 256, n, k); }
  else if (i < OFF_CW2T) { int j = i - OFF_CW1T; int n = j >> 6, k = j & 63;  v = cw1[k * 256 + n];                 dst = frag_idx(OFF_CW1T, 64,  n, k); }
  else if (i < OFF_CW3T) { int j = i - OFF_CW2T; int n = j >> 8, k = j & 255; v = cw2[k * 256 + n];                 dst = frag_idx(OFF_CW2T, 256, n, k); }
  else                   { int j = i - OFF_CW3T; int n = j >> 8, k = j & 255; v = (n == 0) ? cw3[k] : 0.f;          dst = frag_idx(OFF_CW3T, 256, n, k); }
  wb[dst] = __float2bfloat16(v);
}

// ---------------------------------------------------------------------------
__global__ __launch_bounds__(256, 2) void mlp_kernel(
    const float* __restrict__ states, const float* __restrict__ next_states,
    const float* __restrict__ rewards, const float* __restrict__ masks,
    const float* __restrict__ ab1, const float* __restrict__ ag1, const float* __restrict__ an1,
    const float* __restrict__ ab2, const float* __restrict__ ag2, const float* __restrict__ an2,
    const float* __restrict__ ab3,
    const float* __restrict__ cb1, const float* __restrict__ cg1, const float* __restrict__ cn1,
    const float* __restrict__ cb2, const float* __restrict__ cg2, const float* __restrict__ cn2,
    const float* __restrict__ cb3,
    const __hip_bfloat16* __restrict__ wbuf,
    float* __restrict__ deltas, float* __restrict__ out) {
  __shared__ char PB[12288];          // 4 LN param sets (bias|gam|bet) x 256 f32
  __shared__ char WV[4][8192];        // per-wave pre-LN stash
  const int tid = threadIdx.x;
  const int wave = tid >> 6, lane = tid & 63;
  const int c = lane & 15, q = lane >> 4;
  char* ACT = WV[wave];
  const char* W = (const char*)wbuf;
  const int base = blockIdx.x * 64 + wave * 16;   // 16 timesteps per wave

  // ---- stage params: wave w stages LN set w (bias@0, gam@1024, bet@2048) ----
  {
    const float* bsrc = (wave == 0) ? ab1 : (wave == 1) ? ab2 : (wave == 2) ? cb1 : cb2;
    const float* gsrc = (wave == 0) ? ag1 : (wave == 1) ? ag2 : (wave == 2) ? cg1 : cg2;
    const float* nsrc = (wave == 0) ? an1 : (wave == 1) ? an2 : (wave == 2) ? cn1 : cn2;
    char* dst = PB + wave * 3072;
    *(float4*)(dst + lane * 16)        = *(const float4*)(bsrc + lane * 4);
    *(float4*)(dst + 1024 + lane * 16) = *(const float4*)(gsrc + lane * 4);
    *(float4*)(dst + 2048 + lane * 16) = *(const float4*)(nsrc + lane * 4);
  }
  __syncthreads();
  const float* PA1 = (const float*)(PB);
  const float* PA2 = (const float*)(PB + 3072);
  const float* PC1 = (const float*)(PB + 6144);
  const float* PC2 = (const float*)(PB + 9216);

  bf16x8 xf[2], af[8];

  // ---- X(states) -> regs (kept live across actor + critic) ----
  load_x_frags(states + (size_t)base * 64, c, q, xf);

  // ---- ACTOR(states) ----
  layer_reg<64, 4>(xf, W + OFF_AW1T * 2, PA1, ACT, c, q, lane, af);
  __syncthreads();
  layer_reg<256, 2>(af, W + OFF_AW2T * 2, PA2, ACT, c, q, lane, af);
  __syncthreads();
  {
    f32x4 p3[2];
    run_small_reg<2>(af, W + OFF_AW3T * 2, lane, p3);
    softmax_write(p3, ab3, out, base, c, q);
  }
  __syncthreads();

  // ---- CRITIC(states) ---- (xf still live)
  layer_reg<64, 4>(xf, W + OFF_CW1T * 2, PC1, ACT, c, q, lane, af);
  __syncthreads();
  layer_reg<256, 2>(af, W + OFF_CW2T * 2, PC2, ACT, c, q, lane, af);
  __syncthreads();
  float vst[4];
  {
    f32x4 v[1];
    run_small_reg<1>(af, W + OFF_CW3T * 2, lane, v);
    const float b3 = cb3[0];
#pragma unroll
    for (int r = 0; r < 4; ++r) vst[r] = v[0][r] + b3;
  }
  __syncthreads();

  // ---- CRITIC(next_states) ----
  load_x_frags(next_states + (size_t)base * 64, c, q, xf);
  layer_reg<64, 4>(xf, W + OFF_CW1T * 2, PC1, ACT, c, q, lane, af);
  __syncthreads();
  layer_reg<256, 2>(af, W + OFF_CW2T * 2, PC2, ACT, c, q, lane, af);
  __syncthreads();
  {
    f32x4 v[1];
    run_small_reg<1>(af, W + OFF_CW3T * 2, lane, v);
    const float b3 = cb3[0];
    if (c == 0) {
#pragma unroll
      for (int r = 0; r < 4; ++r) {
        const int gr = base + q * 4 + r;
        const float nv = v[0][r] + b3;
        out[(size_t)gr * 20 + 19] = vst[r];   // stash value; gae -> return
        deltas[gr] = rewards[gr] + 0.99f * nv * masks[gr] - vst[r];
      }
    }
  }
}

// ---------------------------------------------------------------------------
// GAE, wave-parallel: each wave owns a 512-elem chunk + 512-elem lookahead.
// Truncation: GL^512 ~ 2e-14. value stashed at out[:,19] -> returns.
__global__ __launch_bounds__(256) void gae_kernel(
    const float* __restrict__ deltas, const float* __restrict__ masks,
    float* __restrict__ out) {
  const int w = (blockIdx.x * blockDim.x + threadIdx.x) >> 6;  // 0..1023
  const int lane = threadIdx.x & 63;
  const int idx0 = w * 512 + lane * 16;

  float d[16], cf[16];
  if (idx0 < T_SZ) {
#pragma unroll
    for (int i = 0; i < 4; ++i) {
      *(float4*)(d + i * 4)  = *(const float4*)(deltas + idx0 + i * 4);
      *(float4*)(cf + i * 4) = *(const float4*)(masks + idx0 + i * 4);
    }
#pragma unroll
    for (int i = 0; i < 16; ++i) cf[i] *= GL;
  } else {
#pragma unroll
    for (int i = 0; i < 16; ++i) { d[i] = 0.f; cf[i] = 0.f; }
  }

  float A = 0.f, P = 1.f;
#pragma unroll
  for (int i = 15; i >= 0; --i) { A = d[i] + cf[i] * A; P *= cf[i]; }

  float As = A, Ps = P;
#pragma unroll
  for (int st = 1; st < 64; st <<= 1) {
    float An = __shfl_down(As, st, 64);
    float Pn = __shfl_down(Ps, st, 64);
    if (lane + st < 64) { As = As + Ps * An; Ps = Ps * Pn; }
  }
  float G = __shfl_down(As, 1, 64);
  if (lane == 63) G = 0.f;

  if (lane < 32) {
    float g = G;
#pragma unroll
    for (int i = 15; i >= 0; --i) {
      g = d[i] + cf[i] * g;
      const size_t j = (size_t)(idx0 + i);
      float val = out[j * 20 + 19];
      out[j * 20 + 18] = g;
      out[j * 20 + 19] = g + val;
    }
  }
}

// ---------------------------------------------------------------------------
extern "C" void kernel_launch(void* const* d_in, const int* in_sizes, int n_in,
                              void* d_out, int out_size, void* d_ws, size_t ws_size,
                              hipStream_t stream) {
  const float* states      = (const float*)d_in[0];
  const float* next_states = (const float*)d_in[1];
  const float* rewards     = (const float*)d_in[2];
  const float* masks       = (const float*)d_in[3];
  const float* aw1 = (const float*)d_in[4];
  const float* ab1 = (const float*)d_in[5];
  const float* ag1 = (const float*)d_in[6];
  const float* an1 = (const float*)d_in[7];
  const float* aw2 = (const float*)d_in[8];
  const float* ab2 = (const float*)d_in[9];
  const float* ag2 = (const float*)d_in[10];
  const float* an2 = (const float*)d_in[11];
  const float* aw3 = (const float*)d_in[12];
  const float* ab3 = (const float*)d_in[13];
  const float* cw1 = (const float*)d_in[14];
  const float* cb1 = (const float*)d_in[15];
  const float* cg1 = (const float*)d_in[16];
  const float* cn1 = (const float*)d_in[17];
  const float* cw2 = (const float*)d_in[18];
  const float* cb2 = (const float*)d_in[19];
  const float* cg2 = (const float*)d_in[20];
  const float* cn2 = (const float*)d_in[21];
  const float* cw3 = (const float*)d_in[22];
  const float* cb3 = (const float*)d_in[23];

  __hip_bfloat16* wbuf = (__hip_bfloat16*)d_ws;
  float* deltas = (float*)((char*)d_ws + OFF_DELTAS_BYTES);
  float* out = (float*)d_out;

  prep_weights<<<(W_ELEMS + 255) / 256, 256, 0, stream>>>(aw1, aw2, aw3, cw1, cw2, cw3, wbuf);
  mlp_kernel<<<T_SZ / 64, 256, 0, stream>>>(
      states, next_states, rewards, masks,
      ab1, ag1, an1, ab2, ag2, an2, ab3,
      cb1, cg1, cn1, cb2, cg2, cn2, cb3,
      wbuf, deltas, out);
  gae_kernel<<<256, 256, 0, stream>>>(deltas, masks, out);
}